// Round 1
// 1502.462 us; speedup vs baseline: 1.0999x; 1.0999x over previous
//
#include <hip/hip_runtime.h>
#include <cstdint>
#include <cstddef>

#define NROWS 65536
#define DIM   256
#define KCB   1024
#define NSTG  3
#define MB    32              // rows per block
#define KT    512             // codes per k-tile (2 k-tiles per stage)
#define DB    8               // d-rows staged per chunk
#define CTS   516             // ct row stride in floats (pad 4)
#define RST   260             // r row stride in floats (pad 4, spreads rows over banks)
#define NCH   (NSTG * 64)     // total chunks: 3 stages * 2 ktiles * 32 di

// 8-wide FMA into one accumulator row (components x..w of CA/CB are 4 codes each)
#define FMA8(RV, CA, CB, ACC) do {                                    \
    (ACC)[0] = fmaf((RV), (CA).x, (ACC)[0]);                          \
    (ACC)[1] = fmaf((RV), (CA).y, (ACC)[1]);                          \
    (ACC)[2] = fmaf((RV), (CA).z, (ACC)[2]);                          \
    (ACC)[3] = fmaf((RV), (CA).w, (ACC)[3]);                          \
    (ACC)[4] = fmaf((RV), (CB).x, (ACC)[4]);                          \
    (ACC)[5] = fmaf((RV), (CB).y, (ACC)[5]);                          \
    (ACC)[6] = fmaf((RV), (CB).z, (ACC)[6]);                          \
    (ACC)[7] = fmaf((RV), (CB).w, (ACC)[7]); } while (0)

// ---------------- codebook row squared norms: c2[row] = sum(cb[row]^2) ----------------
__global__ void c2_kernel(const float* __restrict__ cb, float* __restrict__ c2) {
    int row  = blockIdx.x * 4 + (threadIdx.x >> 6);   // one wave per codebook row
    int lane = threadIdx.x & 63;
    float4 v = ((const float4*)(cb + (size_t)row * DIM))[lane];
    float s = v.x * v.x + v.y * v.y + v.z * v.z + v.w * v.w;
#pragma unroll
    for (int m = 32; m >= 1; m >>= 1) s += __shfl_xor(s, m, 64);
    if (lane == 0) c2[row] = s;
}

// ---------------- fused 3-stage residual VQ ----------------
// Geometry: 4 waves; wave ty owns rows [8ty,8ty+8); lane tx owns codes
// {4tx..4tx+3} and {256+4tx..259+4tx} within each 512-code k-tile (8x8 reg tile).
// r columns are stored XOR-swizzled: phys = col ^ (((col>>5)&7)<<2), row stride 260.
__global__ __launch_bounds__(256, 2)
void rvq_kernel(const float* __restrict__ z, const float* __restrict__ cb,
                const float* __restrict__ c2g, float* __restrict__ out,
                float* __restrict__ loss_acc) {
    __shared__ __align__(16) float r[MB * RST];        // 33280 B residual tile
    __shared__ __align__(16) float ct[2][DB][CTS];     // 33024 B dbuf codebook chunk [d][code]
    __shared__ __align__(16) float c2s[KCB];           // 4 KB per-stage code norms
    __shared__ float l2s[MB];
    __shared__ int   bestk[MB];
    __shared__ float redw[4];

    const int tid = threadIdx.x;
    const int tx  = tid & 63;          // lane within wave
    const int ty  = tid >> 6;          // wave id: rows 8ty..8ty+7
    const int tx4 = tx * 4;
    const size_t rowbase = (size_t)blockIdx.x * MB;

    // ---- prologue prefetch of chunk 0 (stage 0, kt 0, d0=0): codes {tid, tid+256} ----
    float4 pv[4];
    {
        const float* p0 = cb + (size_t)tid * DIM;
        const float* p1 = p0 + (size_t)256 * DIM;
        pv[0] = ((const float4*)p0)[0];
        pv[1] = ((const float4*)p0)[1];
        pv[2] = ((const float4*)p1)[0];
        pv[3] = ((const float4*)p1)[1];
    }

    // swizzled column for the linear z-load / output mapping (col = 4*(tid&63))
    const int zp = ((tid & 63) * 4) ^ (((tid & 63) >> 3) << 2);

    // ---- load z tile (coalesced float4) into swizzled r ----
    {
        const float4* zv = (const float4*)(z + rowbase * DIM);
#pragma unroll
        for (int i = 0; i < 8; ++i) {
            float4 v = zv[i * 256 + tid];
            int row = i * 4 + (tid >> 6);
            *(float4*)&r[row * RST + zp] = v;
        }
    }
    __syncthreads();

    // ---- initial per-row l2 = sum(z^2) (same math/order as before) ----
    {
        int row = tid >> 3, ch = tid & 7;
        float s = 0.f;
#pragma unroll
        for (int m = 0; m < 8; ++m) {
            float4 v = *(const float4*)&r[row * RST + ch * 32 + 4 * (m ^ ch)];
            s += v.x * v.x + v.y * v.y + v.z * v.z + v.w * v.w;
        }
        s += __shfl_xor(s, 1, 8);
        s += __shfl_xor(s, 2, 8);
        s += __shfl_xor(s, 4, 8);
        if (ch == 0) l2s[row] = s;
    }

    float4 q[8] = {};                  // straight-through accumulator (32 elems/thread)
    float lossp = 0.f;

#pragma unroll 1
    for (int stage = 0; stage < NSTG; ++stage) {
        __syncthreads();               // old c2s readers done before overwrite
        *(float4*)&c2s[tid * 4] = *(const float4*)&c2g[stage * KCB + tid * 4];

        unsigned long long keys[8];
#pragma unroll
        for (int i = 0; i < 8; ++i) keys[i] = ~0ull;

#pragma unroll 1
        for (int kt = 0; kt < 2; ++kt) {
            float acc[8][8] = {};
#pragma unroll 1
            for (int di = 0; di < 32; ++di) {
                const int c = stage * 64 + kt * 32 + di;
                // ---- stage prefetched chunk into ct[c&1] (transpose: [d][code]) ----
                {
                    float* b = &ct[c & 1][0][0];
                    const int t2 = tid + 256;
                    b[0 * CTS + tid] = pv[0].x;  b[1 * CTS + tid] = pv[0].y;
                    b[2 * CTS + tid] = pv[0].z;  b[3 * CTS + tid] = pv[0].w;
                    b[4 * CTS + tid] = pv[1].x;  b[5 * CTS + tid] = pv[1].y;
                    b[6 * CTS + tid] = pv[1].z;  b[7 * CTS + tid] = pv[1].w;
                    b[0 * CTS + t2]  = pv[2].x;  b[1 * CTS + t2]  = pv[2].y;
                    b[2 * CTS + t2]  = pv[2].z;  b[3 * CTS + t2]  = pv[2].w;
                    b[4 * CTS + t2]  = pv[3].x;  b[5 * CTS + t2]  = pv[3].y;
                    b[6 * CTS + t2]  = pv[3].z;  b[7 * CTS + t2]  = pv[3].w;
                }
                __syncthreads();       // single barrier per chunk (dbuf handles WAR)
                // ---- issue next chunk's global loads AFTER the barrier (no vmcnt drain) ----
                if (c + 1 < NCH) {
                    const int cn = c + 1;
                    const int s2 = cn >> 6, k2 = (cn >> 5) & 1, d2 = (cn & 31) * 8;
                    const float* p0 = cb + ((size_t)(s2 * KCB + k2 * KT) + tid) * DIM + d2;
                    const float* p1 = p0 + (size_t)256 * DIM;
                    pv[0] = ((const float4*)p0)[0];
                    pv[1] = ((const float4*)p0)[1];
                    pv[2] = ((const float4*)p1)[0];
                    pv[3] = ((const float4*)p1)[1];
                }
                // ---- 8x8 register micro-GEMM over this 8-deep d-chunk ----
                {
                    const float (*cc)[CTS] = ct[c & 1];
                    const int d0 = di * 8;
#pragma unroll
                    for (int dd = 0; dd < 8; dd += 4) {
                        const int dc = d0 + dd;
                        const int pc = dc ^ (((dc >> 5) & 7) << 2);
                        float4 rf[8];
#pragma unroll
                        for (int i = 0; i < 8; ++i)
                            rf[i] = *(const float4*)&r[(ty * 8 + i) * RST + pc];
                        float4 ca, cbv;
                        ca  = *(const float4*)&cc[dd + 0][tx4];
                        cbv = *(const float4*)&cc[dd + 0][tx4 + 256];
#pragma unroll
                        for (int i = 0; i < 8; ++i) FMA8(rf[i].x, ca, cbv, acc[i]);
                        ca  = *(const float4*)&cc[dd + 1][tx4];
                        cbv = *(const float4*)&cc[dd + 1][tx4 + 256];
#pragma unroll
                        for (int i = 0; i < 8; ++i) FMA8(rf[i].y, ca, cbv, acc[i]);
                        ca  = *(const float4*)&cc[dd + 2][tx4];
                        cbv = *(const float4*)&cc[dd + 2][tx4 + 256];
#pragma unroll
                        for (int i = 0; i < 8; ++i) FMA8(rf[i].z, ca, cbv, acc[i]);
                        ca  = *(const float4*)&cc[dd + 3][tx4];
                        cbv = *(const float4*)&cc[dd + 3][tx4 + 256];
#pragma unroll
                        for (int i = 0; i < 8; ++i) FMA8(rf[i].w, ca, cbv, acc[i]);
                    }
                }
            }
            // ---- finalize this k-tile, np-rounding-exact:
            // d = (l2 - (2*cl)) + c2, each op rounded separately
            {
                const int kb0 = kt * KT + tx4;
                const int kb1 = kb0 + 256;
                float4 c2a = *(const float4*)&c2s[kb0];
                float4 c2b = *(const float4*)&c2s[kb1];
#pragma unroll
                for (int i = 0; i < 8; ++i) {
                    float l2v = l2s[ty * 8 + i];
#define KEYMIN(AJ, CJ, IDX) do {                                               \
    float dist_ = __fadd_rn(__fsub_rn(l2v, __fmul_rn(2.0f, (AJ))), (CJ));      \
    unsigned long long kk_ =                                                   \
        ((unsigned long long)__float_as_uint(dist_) << 32) | (unsigned)(IDX);  \
    keys[i] = keys[i] < kk_ ? keys[i] : kk_; } while (0)
                    KEYMIN(acc[i][0], c2a.x, kb0 + 0);
                    KEYMIN(acc[i][1], c2a.y, kb0 + 1);
                    KEYMIN(acc[i][2], c2a.z, kb0 + 2);
                    KEYMIN(acc[i][3], c2a.w, kb0 + 3);
                    KEYMIN(acc[i][4], c2b.x, kb1 + 0);
                    KEYMIN(acc[i][5], c2b.y, kb1 + 1);
                    KEYMIN(acc[i][6], c2b.z, kb1 + 2);
                    KEYMIN(acc[i][7], c2b.w, kb1 + 3);
#undef KEYMIN
                }
            }
        }

        // ---- argmin reduce across the full wave (ties -> lowest k) ----
#pragma unroll
        for (int i = 0; i < 8; ++i) {
            unsigned long long k = keys[i];
#pragma unroll
            for (int m = 1; m < 64; m <<= 1) {
                unsigned long long o = __shfl_xor(k, m, 64);
                k = k < o ? k : o;
            }
            if (tx == 0) bestk[ty * 8 + i] = (int)(k & 0xffffffffu);
        }
        __syncthreads();

        // ---- phase B: straight-through update, loss, next-stage l2 ----
        {
            int row = tid >> 3, ch = tid & 7;
            int bk = bestk[row];
            const float4* crow = (const float4*)(cb + ((size_t)stage * KCB + bk) * DIM + ch * 32);
            float* rrow = &r[row * RST];
            float l2p = 0.f;
#pragma unroll
            for (int m = 0; m < 8; ++m) {
                int pcol = ch * 32 + 4 * (m ^ ch);
                float4 rv = *(const float4*)(rrow + pcol);
                float4 cv = crow[m];
                float t0 = __fsub_rn(cv.x, rv.x);
                float t1 = __fsub_rn(cv.y, rv.y);
                float t2 = __fsub_rn(cv.z, rv.z);
                float t3 = __fsub_rn(cv.w, rv.w);
                float s0 = __fadd_rn(rv.x, t0);
                float s1 = __fadd_rn(rv.y, t1);
                float s2 = __fadd_rn(rv.z, t2);
                float s3 = __fadd_rn(rv.w, t3);
                lossp += t0 * t0 + t1 * t1 + t2 * t2 + t3 * t3;
                if (stage == 0) {
                    q[m] = make_float4(s0, s1, s2, s3);
                } else {
                    q[m].x = __fadd_rn(q[m].x, s0);
                    q[m].y = __fadd_rn(q[m].y, s1);
                    q[m].z = __fadd_rn(q[m].z, s2);
                    q[m].w = __fadd_rn(q[m].w, s3);
                }
                if (stage < NSTG - 1) {
                    float n0 = __fsub_rn(rv.x, s0);
                    float n1 = __fsub_rn(rv.y, s1);
                    float n2 = __fsub_rn(rv.z, s2);
                    float n3 = __fsub_rn(rv.w, s3);
                    l2p += n0 * n0 + n1 * n1 + n2 * n2 + n3 * n3;
                    *(float4*)(rrow + pcol) = make_float4(n0, n1, n2, n3);
                } else {
                    *(float4*)(rrow + pcol) = q[m];   // park q for coalesced store
                }
            }
            if (stage < NSTG - 1) {
                l2p += __shfl_xor(l2p, 1, 8);
                l2p += __shfl_xor(l2p, 2, 8);
                l2p += __shfl_xor(l2p, 4, 8);
                if (ch == 0) l2s[row] = l2p;
            }
        }
    }

    __syncthreads();
    // ---- coalesced output write ----
    {
        float4* ov = (float4*)(out + rowbase * DIM);
#pragma unroll
        for (int i = 0; i < 8; ++i) {
            int row = i * 4 + (tid >> 6);
            ov[i * 256 + tid] = *(const float4*)&r[row * RST + zp];
        }
    }

    // ---- loss reduction: wave shuffle -> block -> one atomic ----
    float v = lossp;
#pragma unroll
    for (int m = 32; m >= 1; m >>= 1) v += __shfl_xor(v, m, 64);
    if ((tid & 63) == 0) redw[tid >> 6] = v;
    __syncthreads();
    if (tid == 0) atomicAdd(loss_acc, redw[0] + redw[1] + redw[2] + redw[3]);
}

// ---------------- finalize scalars ----------------
__global__ void fin_kernel(const float* __restrict__ loss_acc, float* __restrict__ out) {
    if (threadIdx.x == 0) {
        float m = loss_acc[0] / (float)((size_t)NROWS * DIM);
        out[(size_t)NROWS * DIM + 0] = m;   // codebook_loss
        out[(size_t)NROWS * DIM + 1] = m;   // commitment_loss (== forward value)
    }
}

extern "C" void kernel_launch(void* const* d_in, const int* in_sizes, int n_in,
                              void* d_out, int out_size, void* d_ws, size_t ws_size,
                              hipStream_t stream) {
    const float* z  = (const float*)d_in[0];
    const float* cb = (const float*)d_in[1];
    float* out = (float*)d_out;
    float* ws  = (float*)d_ws;
    float* c2  = ws + 16;                       // 3*1024 floats at byte offset 64

    hipMemsetAsync(ws, 0, 64, stream);          // zero the loss accumulator
    hipLaunchKernelGGL(c2_kernel, dim3(NSTG * KCB / 4), dim3(256), 0, stream, cb, c2);
    hipLaunchKernelGGL(rvq_kernel, dim3(NROWS / MB), dim3(256), 0, stream,
                       z, cb, c2, out, ws);
    hipLaunchKernelGGL(fin_kernel, dim3(1), dim3(64), 0, stream, ws, out);
}